// Round 17
// baseline (153.573 us; speedup 1.0000x reference)
//
#include <hip/hip_runtime.h>
#include <math.h>

// EnhancedTripletLoss, B=8192, D=256, 8 classes.
// R17: LABEL-SORTED triangular mining. k_perm buckets anchors by label
// (padded to 128-row tiles, T<=72 tiles); every tile-pair block is then
// pure-positive (same bucket: max-only, no label compare) or pure-negative
// (different buckets: min-only). Epilogue ops/pair drop ~15 -> ~8 and the
// eq-branch disappears. Single slotted partial array (slot class derived
// from bucket match in k_finish; R15-proven coverage, no init needed).
// Keys (q18(v)<<14)|jp, v = sq_j - 2*dot (monotone); dummies lose via
// sqqP=0 / sqqN=262143. Exact fp32 recompute via perm in k_finish.

typedef __attribute__((ext_vector_type(8))) short short8;
typedef __attribute__((ext_vector_type(4))) float floatx4;

#define B_N  8192
#define BPAD 9216     // 72 tiles x 128
#define D_K  256
#define NT   72       // max tiles

__device__ __forceinline__ unsigned short f2bf_rne(float f) {
  unsigned u = __float_as_uint(f);
  u += 0x7FFFu + ((u >> 16) & 1u);
  return (unsigned short)(u >> 16);
}

// ---- bucket-sort by label: perm, tile->bucket map, tile count ----
__global__ void k_perm(const int* __restrict__ lab, int* __restrict__ perm,
                       int* __restrict__ tb, int* __restrict__ Tdev,
                       float* __restrict__ sum, int* __restrict__ cnt,
                       int* __restrict__ done) {
  __shared__ int lcnt[8][256];
  __shared__ int c32[8][8];
  __shared__ int S[8];
  const int tid = threadIdx.x;

  for (int i = tid; i < BPAD; i += 256) perm[i] = -1;

  int ll[32], c[8];
#pragma unroll
  for (int l = 0; l < 8; ++l) c[l] = 0;
  const int base = tid * 32;
#pragma unroll
  for (int k = 0; k < 32; ++k) { ll[k] = lab[base + k] & 7; c[ll[k]]++; }
#pragma unroll
  for (int l = 0; l < 8; ++l) lcnt[l][tid] = c[l];
  __syncthreads();

  if (tid < 64) {                       // group sums: l = tid>>3, g = tid&7
    int l = tid >> 3, g = tid & 7, s = 0;
    for (int t2 = g * 32; t2 < g * 32 + 32; ++t2) s += lcnt[l][t2];
    c32[l][g] = s;
  }
  __syncthreads();

  if (tid == 0) {
    int s = 0;
    for (int l = 0; l < 8; ++l) {
      int tot = 0;
      for (int g = 0; g < 8; ++g) { int v = c32[l][g]; c32[l][g] = tot; tot += v; }
      S[l] = s;
      s += (tot + 127) & ~127;          // pad bucket to multiple of 128
    }
    int T = s >> 7;
    Tdev[0] = T;
    int l = 0, acc2 = 0, pl = 0;
    for (int t = 0; t < T; ++t) {       // tile -> bucket
      while (t * 128 >= acc2 + ((l < 8) ? 0 : 0) && l < 8) {
        int tot = (l + 1 < 8 ? S[l + 1] : s) - S[l];
        if (t * 128 < S[l] + tot) break;
        ++l;
      }
      tb[t] = l;
      (void)acc2; (void)pl;
    }
    *sum = 0.f; *cnt = 0; *done = 0;
  }
  __syncthreads();

  int ofs[8];
  {
    int g = tid >> 5;
#pragma unroll
    for (int l = 0; l < 8; ++l) ofs[l] = S[l] + c32[l][g];
    for (int t2 = tid & ~31; t2 < tid; ++t2)
#pragma unroll
      for (int l = 0; l < 8; ++l) ofs[l] += lcnt[l][t2];
  }
#pragma unroll
  for (int k = 0; k < 32; ++k) {
    int l = ll[k];
    perm[ofs[l]++] = base + k;
  }
}

// ---- split (gathered through perm) to bf16 fragment-major + quantized norms ----
// Tile (16 rows x 32 k) = 512 ushorts at [tile_row][tk][lane*8+j].
__global__ void k_split(const float* __restrict__ x, const int* __restrict__ perm,
                        unsigned short* __restrict__ xhf,
                        float* __restrict__ sqqP, float* __restrict__ sqqN) {
  __shared__ float sw[64];
  const int tid  = threadIdx.x;
  const int lane = tid & 63;
  const int w    = tid >> 6;
  const int b    = blockIdx.x;        // dst tile_row over BPAD
  const int m    = lane & 15;
  const int quad = lane >> 4;
  const int o    = perm[b * 16 + m];  // source row (or -1 = dummy)

  float s = 0.f;
#pragma unroll
  for (int h = 0; h < 2; ++h) {
    int tk = w + h * 4;
    int kk = tk * 32 + quad * 8;
    float4 f0 = make_float4(0.f, 0.f, 0.f, 0.f), f1 = f0;
    if (o >= 0) {
      f0 = *reinterpret_cast<const float4*>(x + (size_t)o * D_K + kk);
      f1 = *reinterpret_cast<const float4*>(x + (size_t)o * D_K + kk + 4);
    }
    s += f0.x * f0.x + f0.y * f0.y + f0.z * f0.z + f0.w * f0.w;
    s += f1.x * f1.x + f1.y * f1.y + f1.z * f1.z + f1.w * f1.w;
    ushort4 lo, hi;
    lo.x = f2bf_rne(f0.x); lo.y = f2bf_rne(f0.y); lo.z = f2bf_rne(f0.z); lo.w = f2bf_rne(f0.w);
    hi.x = f2bf_rne(f1.x); hi.y = f2bf_rne(f1.y); hi.z = f2bf_rne(f1.z); hi.w = f2bf_rne(f1.w);
    size_t oo = ((size_t)b * 8 + tk) * 512 + lane * 8;
    *reinterpret_cast<ushort4*>(xhf + oo)     = lo;
    *reinterpret_cast<ushort4*>(xhf + oo + 4) = hi;
  }
  s += __shfl_xor(s, 16);
  s += __shfl_xor(s, 32);
  if (quad == 0) sw[w * 16 + m] = s;
  __syncthreads();
  if (tid < 16) {
    int p  = b * 16 + tid;
    int oo = perm[p];
    float t = sw[tid] + sw[16 + tid] + sw[32 + tid] + sw[48 + tid];
    float q = fmaf(t, 64.f, 131072.f);  // pre-quantized (step 1/64, 18 bits)
    sqqP[p] = (oo >= 0) ? q : 0.f;       // dummy loses pos-max
    sqqN[p] = (oo >= 0) ? q : 262143.f;  // dummy loses neg-min
  }
}

// ---- MFMA Gram + specialized two-sided mining over the tile triangle ----
__global__ __launch_bounds__(256) void k_mine17(
    const unsigned short* __restrict__ xhf, const int* __restrict__ tb,
    const int* __restrict__ Tdev,
    const float* __restrict__ sqqP, const float* __restrict__ sqqN,
    unsigned* __restrict__ part) {
  __shared__ unsigned short Alds[8 * 8 * 512];   // 64 KB

  // decode linear block id -> (bi, bj), bi <= bj, over NT x NT grid
  int t  = blockIdx.x;
  int bi = (int)(72.5f - sqrtf(72.5f * 72.5f - 2.f * (float)t));
  int b0 = 72 * bi - (bi * (bi - 1)) / 2;
  if (t < b0) { bi--; b0 = 72 * bi - (bi * (bi - 1)) / 2; }
  else {
    int b1 = 72 * (bi + 1) - ((bi + 1) * bi) / 2;
    if (t >= b1) { bi++; b0 = b1; }
  }
  const int bj = bi + (t - b0);
  const int T  = Tdev[0];
  if (bj >= T) return;
  const bool same = (tb[bi] == tb[bj]);
  const float* __restrict__ sqc = same ? sqqP : sqqN;

  const int tid  = threadIdx.x;
  const int lane = tid & 63;
  const int w    = tid >> 6;
  const int wi   = w >> 1, wj = w & 1;
  const int quad = lane >> 4, l15 = lane & 15;
  const int i0   = bi * 128;

  {
    const short8* src = reinterpret_cast<const short8*>(xhf + (size_t)bi * 32768);
    short8* dst = reinterpret_cast<short8*>(Alds);
#pragma unroll
    for (int it = 0; it < 16; ++it) dst[it * 256 + tid] = src[it * 256 + tid];
  }

  unsigned key[16];
  float    sqi[16];
#pragma unroll
  for (int r = 0; r < 16; ++r) {
    key[r] = same ? 0u : 0xFFFFFFFFu;
    int ir = i0 + wi * 64 + (r >> 2) * 16 + quad * 4 + (r & 3);
    sqi[r] = sqc[ir];
  }
  __syncthreads();   // the only barrier

  const unsigned short* Bw = xhf + ((size_t)(bj * 8 + wj * 4) * 8) * 512 + lane * 8;
  const unsigned short* Aw = Alds + (size_t)wi * 32 * 512 + lane * 8;

  floatx4 acc[16];
#pragma unroll
  for (int q = 0; q < 16; ++q) acc[q] = (floatx4)0.f;

#pragma unroll
  for (int tk = 0; tk < 8; ++tk) {
    short8 Bf[4];
#pragma unroll
    for (int nt = 0; nt < 4; ++nt)
      Bf[nt] = *reinterpret_cast<const short8*>(Bw + nt * 4096 + tk * 512);
    short8 Af[4];
#pragma unroll
    for (int mt = 0; mt < 4; ++mt)
      Af[mt] = *reinterpret_cast<const short8*>(Aw + (size_t)(mt * 8 + tk) * 512);
#pragma unroll
    for (int mt = 0; mt < 4; ++mt)
#pragma unroll
      for (int nt = 0; nt < 4; ++nt)
        acc[mt * 4 + nt] = __builtin_amdgcn_mfma_f32_16x16x32_bf16(
            Af[mt], Bf[nt], acc[mt * 4 + nt], 0, 0, 0);
  }

  // specialized two-sided epilogue: key = (cvt(sq64 - 128*dot) << 14) | idx.
  // pos blocks (same bucket): umax only; neg blocks: umin only. Self never
  // wins pos-max (v_self = -sq is the row minimum among same-label).
  if (same) {
#pragma unroll
    for (int nt = 0; nt < 4; ++nt) {
      int   j  = bj * 128 + wj * 64 + nt * 16 + l15;
      float sj = sqc[j];
      unsigned jp = 0u;
#pragma unroll
      for (int r = 0; r < 16; ++r) {
        float dot = acc[(r >> 2) * 4 + nt][r & 3];
        int   ir  = i0 + wi * 64 + (r >> 2) * 16 + quad * 4 + (r & 3);
        unsigned keyi = ((unsigned)fmaf(-128.f, dot, sj) << 14) | (unsigned)j;
        key[r] = key[r] > keyi ? key[r] : keyi;
        unsigned keyj = ((unsigned)fmaf(-128.f, dot, sqi[r]) << 14) | (unsigned)ir;
        jp = jp > keyj ? jp : keyj;
      }
#pragma unroll
      for (int m = 16; m < 64; m <<= 1) {
        unsigned op = (unsigned)__shfl_xor((int)jp, m);
        jp = jp > op ? jp : op;
      }
      if (quad == 0 && bi != bj)
        part[(size_t)(2 * bi + wi) * BPAD + j] = jp;
    }
  } else {
#pragma unroll
    for (int nt = 0; nt < 4; ++nt) {
      int   j  = bj * 128 + wj * 64 + nt * 16 + l15;
      float sj = sqc[j];
      unsigned jn = 0xFFFFFFFFu;
#pragma unroll
      for (int r = 0; r < 16; ++r) {
        float dot = acc[(r >> 2) * 4 + nt][r & 3];
        int   ir  = i0 + wi * 64 + (r >> 2) * 16 + quad * 4 + (r & 3);
        unsigned keyi = ((unsigned)fmaf(-128.f, dot, sj) << 14) | (unsigned)j;
        key[r] = key[r] < keyi ? key[r] : keyi;
        unsigned keyj = ((unsigned)fmaf(-128.f, dot, sqi[r]) << 14) | (unsigned)ir;
        jn = jn < keyj ? jn : keyj;
      }
#pragma unroll
      for (int m = 16; m < 64; m <<= 1) {
        unsigned on = (unsigned)__shfl_xor((int)jn, m);
        jn = jn < on ? jn : on;
      }
      if (quad == 0)
        part[(size_t)(2 * bi + wi) * BPAD + j] = jn;
    }
  }

  // i-side: reduce across the 16 l15-lanes, publish slot 2*bj+wj of band bi
#pragma unroll
  for (int r = 0; r < 16; ++r) {
    unsigned p = key[r];
    if (same) {
#pragma unroll
      for (int m = 1; m < 16; m <<= 1) {
        unsigned op = (unsigned)__shfl_xor((int)p, m);
        p = p > op ? p : op;
      }
    } else {
#pragma unroll
      for (int m = 1; m < 16; m <<= 1) {
        unsigned op = (unsigned)__shfl_xor((int)p, m);
        p = p < op ? p : op;
      }
    }
    if (l15 == 0) {
      int ir = i0 + wi * 64 + (r >> 2) * 16 + quad * 4 + (r & 3);
      part[(size_t)(2 * bj + wj) * BPAD + ir] = p;
    }
  }
}

// ---- slot-reduce (classified by bucket match) + exact distances + loss ----
__global__ void k_finish(const float* __restrict__ x, const int* __restrict__ perm,
                         const int* __restrict__ tb, const int* __restrict__ Tdev,
                         const unsigned* __restrict__ part,
                         float* __restrict__ sum, int* __restrict__ cnt,
                         int* __restrict__ done, float* __restrict__ out) {
  __shared__ unsigned spk[32], snk[32];
  __shared__ float ssum[4];
  __shared__ int   scnt[4];
  const int tid  = threadIdx.x;
  const int a0   = blockIdx.x * 32;
  const int T    = Tdev[0];
  const int myb  = tb[a0 >> 7];        // band uniform per block (32 | 128)

  if (tid < 32) { spk[tid] = 0u; snk[tid] = 0xFFFFFFFFu; }
  __syncthreads();

  {
    const int a    = a0 + (tid & 31);
    const int g    = tid >> 5;          // 8 groups x 18 slots
    unsigned p = 0u, n = 0xFFFFFFFFu;
    int send = g * 18 + 18;
    if (send > 2 * T) send = 2 * T;
    for (int s = g * 18; s < send; ++s) {
      unsigned v = part[(size_t)s * BPAD + a];
      if (tb[s >> 1] == myb) { p = p > v ? p : v; }
      else                   { n = n < v ? n : v; }
    }
    atomicMax(&spk[tid & 31], p);
    atomicMin(&snk[tid & 31], n);
  }
  __syncthreads();

  const int w = tid >> 6, lane = tid & 63;
  float lsum = 0.f; int lcnt2 = 0;
#pragma unroll
  for (int it = 0; it < 8; ++it) {
    int al = w * 8 + it;
    int a  = a0 + al;
    int o  = perm[a];
    unsigned p = spk[al];
    unsigned n = snk[al];
    bool valid = (o >= 0) && (p != 0u) && (n != 0xFFFFFFFFu);
    int  pidx = valid ? perm[p & 16383u] : 0;
    int  nidx = valid ? perm[n & 16383u] : 0;
    int  ao   = valid ? o : 0;

    float4 xa = *reinterpret_cast<const float4*>(x + (size_t)ao * D_K + lane * 4);
    float4 xp = *reinterpret_cast<const float4*>(x + (size_t)pidx * D_K + lane * 4);
    float4 xn = *reinterpret_cast<const float4*>(x + (size_t)nidx * D_K + lane * 4);
    float dx, sp = 0.f, sn = 0.f;
    dx = xa.x - xp.x + 1e-6f; sp = fmaf(dx, dx, sp);
    dx = xa.y - xp.y + 1e-6f; sp = fmaf(dx, dx, sp);
    dx = xa.z - xp.z + 1e-6f; sp = fmaf(dx, dx, sp);
    dx = xa.w - xp.w + 1e-6f; sp = fmaf(dx, dx, sp);
    dx = xa.x - xn.x + 1e-6f; sn = fmaf(dx, dx, sn);
    dx = xa.y - xn.y + 1e-6f; sn = fmaf(dx, dx, sn);
    dx = xa.z - xn.z + 1e-6f; sn = fmaf(dx, dx, sn);
    dx = xa.w - xn.w + 1e-6f; sn = fmaf(dx, dx, sn);
#pragma unroll
    for (int o2 = 32; o2 > 0; o2 >>= 1) {
      sp += __shfl_down(sp, o2, 64);
      sn += __shfl_down(sn, o2, 64);
    }
    if (lane == 0 && valid) {
      float per = sqrtf(sp) - sqrtf(sn) + 0.3f;
      if (per > 0.f) lsum += per;
      lcnt2 += 1;
    }
  }
  if (lane == 0) { ssum[w] = lsum; scnt[w] = lcnt2; }
  __syncthreads();
  if (tid == 0) {
    atomicAdd(sum, ssum[0] + ssum[1] + ssum[2] + ssum[3]);
    atomicAdd(cnt, scnt[0] + scnt[1] + scnt[2] + scnt[3]);
    __threadfence();
    int prev = atomicAdd(done, 1);
    if (prev == gridDim.x - 1) {
      float s = atomicAdd(sum, 0.f);
      int   cc = atomicAdd(cnt, 0);
      if (cc < 1) cc = 1;
      out[0] = s / (float)cc;
    }
  }
}

extern "C" void kernel_launch(void* const* d_in, const int* in_sizes, int n_in,
                              void* d_out, int out_size, void* d_ws, size_t ws_size,
                              hipStream_t stream) {
  const float* x   = (const float*)d_in[0];
  const int*   lab = (const int*)d_in[1];
  float*       out = (float*)d_out;

  char* ws = (char*)d_ws;
  unsigned short* xhf = (unsigned short*)ws;                       // 4608 KB
  float* sqqP = (float*)(ws + (size_t)4608 * 1024);                // 36 KB
  float* sqqN = (float*)(ws + (size_t)4648 * 1024);                // 36 KB
  int*   perm = (int*)(ws + (size_t)4688 * 1024);                  // 36 KB
  int*   tb   = (int*)(ws + (size_t)4728 * 1024);                  // 288 B
  int*   Tdev = (int*)(ws + (size_t)4729 * 1024);
  unsigned* part = (unsigned*)(ws + (size_t)4732 * 1024);          // 5184 KB
  float* sum  = (float*)(ws + (size_t)9920 * 1024);
  int*   cnt  = (int*)(sum + 1);
  int*   done = (int*)(sum + 2);

  k_perm<<<1, 256, 0, stream>>>(lab, perm, tb, Tdev, sum, cnt, done);
  k_split<<<BPAD / 16, 256, 0, stream>>>(x, perm, xhf, sqqP, sqqN);
  k_mine17<<<NT * (NT + 1) / 2, 256, 0, stream>>>(xhf, tb, Tdev, sqqP, sqqN, part);
  k_finish<<<BPAD / 32, 256, 0, stream>>>(x, perm, tb, Tdev, part, sum, cnt, done, out);
}

// Round 18
// 122.763 us; speedup vs baseline: 1.2510x; 1.2510x over previous
//
#include <hip/hip_runtime.h>
#include <math.h>

// EnhancedTripletLoss, B=8192, D=256, 8 classes.
// R18 = R16 (measured best, 121.7us): triangular two-sided slotted mine
// (no global atomics — R15's fix, worth -30us), 512-thread blocks: 8 waves
// (4 wi x 2 wj), wave tile 32x64, sharing one 64 KB A-panel -> 16 waves/CU.
// j-side combined across wi-wave pairs via 4 KB LDS so the R15 slot scheme
// (j-side 2bi+{0,1}, i-side 2bj+wj, no holes, no init) holds. R17's label-
// sort variant improved mine -5.7us but cost +37us pipeline overhead — reverted.
// Keys (q(v)<<13)|idx, v = sq_j - 2*dot (monotone); exact fp32 recompute in
// k_finish (F.pairwise_distance eps semantics).

typedef __attribute__((ext_vector_type(8))) short short8;
typedef __attribute__((ext_vector_type(4))) float floatx4;

#define B_N 8192
#define D_K 256

__device__ __forceinline__ unsigned short f2bf_rne(float f) {
  unsigned u = __float_as_uint(f);
  u += 0x7FFFu + ((u >> 16) & 1u);
  return (unsigned short)(u >> 16);
}

// ---- split to bf16 fragment-major + quantized row norms ----
// Tile (16 rows x 32 k) = 512 ushorts at [tile_row][tk][lane*8+j]:
// lane = quad*16 + m, row = 16*tile_row + m, k = 32*tk + quad*8 + j.
__global__ void k_split(const float* __restrict__ x, unsigned short* __restrict__ xhf,
                        float* __restrict__ sqq,
                        float* __restrict__ sum, int* __restrict__ cnt,
                        int* __restrict__ done) {
  __shared__ float sw[64];
  const int tid  = threadIdx.x;
  const int lane = tid & 63;
  const int w    = tid >> 6;
  const int b    = blockIdx.x;        // tile_row
  const int m    = lane & 15;
  const int quad = lane >> 4;
  const int row  = b * 16 + m;

  float s = 0.f;
#pragma unroll
  for (int h = 0; h < 2; ++h) {
    int tk = w + h * 4;
    int kk = tk * 32 + quad * 8;
    float4 f0 = *reinterpret_cast<const float4*>(x + (size_t)row * D_K + kk);
    float4 f1 = *reinterpret_cast<const float4*>(x + (size_t)row * D_K + kk + 4);
    s += f0.x * f0.x + f0.y * f0.y + f0.z * f0.z + f0.w * f0.w;
    s += f1.x * f1.x + f1.y * f1.y + f1.z * f1.z + f1.w * f1.w;
    ushort4 lo, hi;
    lo.x = f2bf_rne(f0.x); lo.y = f2bf_rne(f0.y); lo.z = f2bf_rne(f0.z); lo.w = f2bf_rne(f0.w);
    hi.x = f2bf_rne(f1.x); hi.y = f2bf_rne(f1.y); hi.z = f2bf_rne(f1.z); hi.w = f2bf_rne(f1.w);
    size_t o = ((size_t)b * 8 + tk) * 512 + lane * 8;
    *reinterpret_cast<ushort4*>(xhf + o)     = lo;
    *reinterpret_cast<ushort4*>(xhf + o + 4) = hi;
  }
  s += __shfl_xor(s, 16);
  s += __shfl_xor(s, 32);
  if (quad == 0) sw[w * 16 + m] = s;
  __syncthreads();
  if (tid < 16) {
    int i = b * 16 + tid;
    float t = sw[tid] + sw[16 + tid] + sw[32 + tid] + sw[48 + tid];
    sqq[i] = fmaf(t, 128.f, 262144.f);   // pre-quantized for key calc
  }
  if (b == 0 && tid == 0) { *sum = 0.f; *cnt = 0; *done = 0; }
}

// ---- MFMA Gram + two-sided mining, 8 waves/block, no global atomics ----
__global__ __launch_bounds__(512) void k_mine18(
    const unsigned short* __restrict__ xhf, const int* __restrict__ lab,
    const float* __restrict__ sqq,
    unsigned* __restrict__ ppart, unsigned* __restrict__ npart) {
  __shared__ unsigned short Alds[8 * 8 * 512];   // 64 KB: [mtile 8][tk 8][512]
  __shared__ unsigned jbp[8 * 64], jbn[8 * 64];  // 4 KB: per-wave j-side partials

  // decode linear block id -> (bi, bj), bi <= bj, over 64x64 block grid
  int t  = blockIdx.x;
  int bi = (int)(64.5f - sqrtf(64.5f * 64.5f - 2.f * (float)t));
  int b0 = 64 * bi - (bi * (bi - 1)) / 2;
  if (t < b0) { bi--; b0 = 64 * bi - (bi * (bi - 1)) / 2; }
  else {
    int b1 = 64 * (bi + 1) - ((bi + 1) * bi) / 2;
    if (t >= b1) { bi++; b0 = b1; }
  }
  const int bj = bi + (t - b0);

  const int tid  = threadIdx.x;
  const int lane = tid & 63;
  const int w    = tid >> 6;          // 0..7
  const int wi   = w >> 1;            // 0..3 : 32-anchor band
  const int wj   = w & 1;             // 0..1 : 64-j half
  const int quad = lane >> 4, l15 = lane & 15;
  const int i0   = bi * 128;

  // stage A: contiguous 64 KB copy (already fragment-major), 512 threads
  {
    const short8* src = reinterpret_cast<const short8*>(xhf + (size_t)bi * 32768);
    short8* dst = reinterpret_cast<short8*>(Alds);
#pragma unroll
    for (int it = 0; it < 8; ++it) dst[it * 512 + tid] = src[it * 512 + tid];
  }

  // rows of this wave: r = mt*4+reg -> ir = i0 + wi*32 + mt*16 + quad*4 + reg
  unsigned pkey[8], nkey[8];
  unsigned lip = 0;
  float    sqi[8];
#pragma unroll
  for (int r = 0; r < 8; ++r) {
    pkey[r] = 0u; nkey[r] = 0xFFFFFFFFu;
    int ir = i0 + wi * 32 + (r >> 2) * 16 + quad * 4 + (r & 3);
    lip |= ((unsigned)lab[ir] & 0xFu) << (r * 4);
    sqi[r] = sqq[ir];
  }
  __syncthreads();

  const unsigned short* Bw = xhf + ((size_t)(bj * 8 + wj * 4) * 8) * 512 + lane * 8;
  const unsigned short* Aw = Alds + (size_t)(wi * 2) * 8 * 512 + lane * 8;

  floatx4 acc[8];
#pragma unroll
  for (int q = 0; q < 8; ++q) acc[q] = (floatx4)0.f;

#pragma unroll
  for (int tk = 0; tk < 8; ++tk) {
    short8 Bf[4];
#pragma unroll
    for (int nt = 0; nt < 4; ++nt)
      Bf[nt] = *reinterpret_cast<const short8*>(Bw + nt * 4096 + tk * 512);
    short8 Af[2];
#pragma unroll
    for (int mt = 0; mt < 2; ++mt)
      Af[mt] = *reinterpret_cast<const short8*>(Aw + (size_t)(mt * 8 + tk) * 512);
#pragma unroll
    for (int mt = 0; mt < 2; ++mt)
#pragma unroll
      for (int nt = 0; nt < 4; ++nt)
        acc[mt * 4 + nt] = __builtin_amdgcn_mfma_f32_16x16x32_bf16(
            Af[mt], Bf[nt], acc[mt * 4 + nt], 0, 0, 0);
  }

  // two-sided selection epilogue (keys as in R11/R15).
  // i-side: v_ij = sq_j - 2*dot -> key (cvt(sjq-256*dot)<<13)|j, umax/umin.
  // j-side: v_ji = sq_i - 2*dot -> key (cvt(sqi-256*dot)<<13)|i, same eq.
#pragma unroll
  for (int nt = 0; nt < 4; ++nt) {
    int      j  = bj * 128 + wj * 64 + nt * 16 + l15;
    unsigned jl = (unsigned)lab[j] & 0xFu;
    float    sj = sqq[j];
    unsigned jp = 0u, jn = 0xFFFFFFFFu;
#pragma unroll
    for (int r = 0; r < 8; ++r) {
      float dot = acc[(r >> 2) * 4 + nt][r & 3];
      int   ir  = i0 + wi * 32 + (r >> 2) * 16 + quad * 4 + (r & 3);
      bool  eq  = (jl == ((lip >> (r * 4)) & 0xFu));
      // i-side
      unsigned kqi  = (unsigned)fmaf(-256.f, dot, sj);
      unsigned keyi = (kqi << 13) | (unsigned)j;
      unsigned pci = eq ? keyi : 0u;
      unsigned nci = eq ? 0xFFFFFFFFu : keyi;
      pkey[r] = pkey[r] > pci ? pkey[r] : pci;
      nkey[r] = nkey[r] < nci ? nkey[r] : nci;
      // j-side
      unsigned kqj  = (unsigned)fmaf(-256.f, dot, sqi[r]);
      unsigned keyj = (kqj << 13) | (unsigned)ir;
      unsigned pcj = eq ? keyj : 0u;
      unsigned ncj = eq ? 0xFFFFFFFFu : keyj;
      jp = jp > pcj ? jp : pcj;
      jn = jn < ncj ? jn : ncj;
    }
    // reduce j-side across the 4 quads sharing this j, park in LDS
#pragma unroll
    for (int m = 16; m < 64; m <<= 1) {
      unsigned op = (unsigned)__shfl_xor((int)jp, m);
      unsigned on = (unsigned)__shfl_xor((int)jn, m);
      jp = jp > op ? jp : op;
      jn = jn < on ? jn : on;
    }
    if (quad == 0) {
      jbp[w * 64 + nt * 16 + l15] = jp;
      jbn[w * 64 + nt * 16 + l15] = jn;
    }
  }

  // i-side: reduce across the 16 l15-lanes, publish slot 2*bj+wj of band bi
#pragma unroll
  for (int r = 0; r < 8; ++r) {
    unsigned p = pkey[r], n = nkey[r];
#pragma unroll
    for (int m = 1; m < 16; m <<= 1) {
      unsigned op = (unsigned)__shfl_xor((int)p, m);
      unsigned on = (unsigned)__shfl_xor((int)n, m);
      p = p > op ? p : op;
      n = n < on ? n : on;
    }
    if (l15 == 0) {
      int ir = i0 + wi * 32 + (r >> 2) * 16 + quad * 4 + (r & 3);
      size_t idx = (size_t)(2 * bj + wj) * B_N + ir;
      ppart[idx] = p;
      npart[idx] = n;
    }
  }

  __syncthreads();
  // j-side combine across wi-pairs (w and w^2 share wj): waves wi in {0,2}
  // publish slot 2*bi + (wi>>1) of band bj. Diagonal skipped (i-side covers).
  if ((wi & 1) == 0 && bi != bj) {
    unsigned p = jbp[w * 64 + lane];
    unsigned n = jbn[w * 64 + lane];
    unsigned p2 = jbp[(w ^ 2) * 64 + lane];
    unsigned n2 = jbn[(w ^ 2) * 64 + lane];
    p = p > p2 ? p : p2;
    n = n < n2 ? n : n2;
    int j = bj * 128 + wj * 64 + lane;
    size_t idx = (size_t)(2 * bi + (wi >> 1)) * B_N + j;
    ppart[idx] = p;
    npart[idx] = n;
  }
}

// ---- slot-reduce + exact fp32 triplet distances + loss (R15's proven form) ----
__global__ void k_finish(const float* __restrict__ x,
                         const unsigned* __restrict__ ppart,
                         const unsigned* __restrict__ npart,
                         float* __restrict__ sum, int* __restrict__ cnt,
                         int* __restrict__ done, float* __restrict__ out) {
  __shared__ unsigned spk[32], snk[32];
  __shared__ float ssum[4];
  __shared__ int   scnt[4];
  const int tid = threadIdx.x;
  const int a0  = blockIdx.x * 32;

  if (tid < 32) { spk[tid] = 0u; snk[tid] = 0xFFFFFFFFu; }
  __syncthreads();

  {
    const int a    = a0 + (tid & 31);
    const int part = tid >> 5;           // 0..7 -> slots part*16 .. part*16+15
    unsigned p = 0u, n = 0xFFFFFFFFu;
#pragma unroll
    for (int s = 0; s < 16; ++s) {
      size_t idx = (size_t)(part * 16 + s) * B_N + a;
      unsigned pv = ppart[idx];
      unsigned nv = npart[idx];
      p = p > pv ? p : pv;
      n = n < nv ? n : nv;
    }
    atomicMax(&spk[tid & 31], p);        // LDS atomics: cheap, 8-way
    atomicMin(&snk[tid & 31], n);
  }
  __syncthreads();

  const int w = tid >> 6, lane = tid & 63;
  float lsum = 0.f; int lcnt = 0;
#pragma unroll
  for (int it = 0; it < 8; ++it) {
    int al = w * 8 + it;                 // 0..31
    int a  = a0 + al;
    unsigned p = spk[al];
    unsigned n = snk[al];
    bool valid = (p != 0u) && (n != 0xFFFFFFFFu);
    int  pidx = valid ? (int)(p & 8191u) : 0;
    int  nidx = valid ? (int)(n & 8191u) : 0;

    float4 xa = *reinterpret_cast<const float4*>(x + (size_t)a * D_K + lane * 4);
    float4 xp = *reinterpret_cast<const float4*>(x + (size_t)pidx * D_K + lane * 4);
    float4 xn = *reinterpret_cast<const float4*>(x + (size_t)nidx * D_K + lane * 4);
    float dx, sp = 0.f, sn = 0.f;
    dx = xa.x - xp.x + 1e-6f; sp = fmaf(dx, dx, sp);
    dx = xa.y - xp.y + 1e-6f; sp = fmaf(dx, dx, sp);
    dx = xa.z - xp.z + 1e-6f; sp = fmaf(dx, dx, sp);
    dx = xa.w - xp.w + 1e-6f; sp = fmaf(dx, dx, sp);
    dx = xa.x - xn.x + 1e-6f; sn = fmaf(dx, dx, sn);
    dx = xa.y - xn.y + 1e-6f; sn = fmaf(dx, dx, sn);
    dx = xa.z - xn.z + 1e-6f; sn = fmaf(dx, dx, sn);
    dx = xa.w - xn.w + 1e-6f; sn = fmaf(dx, dx, sn);
#pragma unroll
    for (int o = 32; o > 0; o >>= 1) {
      sp += __shfl_down(sp, o, 64);
      sn += __shfl_down(sn, o, 64);
    }
    if (lane == 0 && valid) {
      float per = sqrtf(sp) - sqrtf(sn) + 0.3f;
      if (per > 0.f) lsum += per;
      lcnt += 1;
    }
  }
  if (lane == 0) { ssum[w] = lsum; scnt[w] = lcnt; }
  __syncthreads();
  if (tid == 0) {
    atomicAdd(sum, ssum[0] + ssum[1] + ssum[2] + ssum[3]);
    atomicAdd(cnt, scnt[0] + scnt[1] + scnt[2] + scnt[3]);
    __threadfence();
    int prev = atomicAdd(done, 1);
    if (prev == gridDim.x - 1) {
      float s = atomicAdd(sum, 0.f);
      int   cc = atomicAdd(cnt, 0);
      if (cc < 1) cc = 1;
      out[0] = s / (float)cc;
    }
  }
}

extern "C" void kernel_launch(void* const* d_in, const int* in_sizes, int n_in,
                              void* d_out, int out_size, void* d_ws, size_t ws_size,
                              hipStream_t stream) {
  const float* x   = (const float*)d_in[0];
  const int*   lab = (const int*)d_in[1];
  float*       out = (float*)d_out;

  char* ws = (char*)d_ws;
  unsigned short* xhf = (unsigned short*)ws;                      // 4 MB
  float* sqq = (float*)(ws + (size_t)4608 * 1024);                // 32 KB
  char*  pb = ws + (size_t)4608 * 1024 + 65536;
  size_t seg = (size_t)128 * B_N * 4;                             // 4 MB each
  unsigned* ppart = (unsigned*)(pb);
  unsigned* npart = (unsigned*)(pb + seg);
  float* sum  = (float*)(pb + 2 * seg);
  int*   cnt  = (int*)(sum + 1);
  int*   done = (int*)(sum + 2);

  k_split<<<B_N / 16, 256, 0, stream>>>(x, xhf, sqq, sum, cnt, done);
  k_mine18<<<2080, 512, 0, stream>>>(xhf, lab, sqq, ppart, npart);
  k_finish<<<B_N / 32, 256, 0, stream>>>(x, ppart, npart, sum, cnt, done, out);
}